// Round 2
// baseline (332.119 us; speedup 1.0000x reference)
//
#include <hip/hip_runtime.h>
#include <hip/hip_bf16.h>
#include <stdint.h>

#define BB 16
#define NZ 2048
#define NE 2048
#define DD 512

typedef unsigned short u16;
typedef __attribute__((ext_vector_type(8))) _Float16 f16x8;  // 8 fp16 = 4 VGPR
typedef __attribute__((ext_vector_type(4))) float f32x4;

// ---------- helpers ----------
__device__ __forceinline__ u16 f2h(float f) {
  _Float16 h = (_Float16)f;                 // v_cvt_f16_f32, RNE
  return __builtin_bit_cast(u16, h);
}

__device__ __forceinline__ void gload_lds16(const void* g, void* l) {
  auto gp = (const __attribute__((address_space(1))) uint32_t*)g;
  auto lp = (__attribute__((address_space(3))) uint32_t*)l;
  __builtin_amdgcn_global_load_lds(gp, lp, 16, 0, 0);
}

// ---------- f32 -> fp16 bulk convert ----------
__global__ void k_cvt(const float* __restrict__ in, u16* __restrict__ out, int n4) {
  int i = blockIdx.x * blockDim.x + threadIdx.x;
  int stride = gridDim.x * blockDim.x;
  for (; i < n4; i += stride) {
    float4 v = ((const float4*)in)[i];
    ushort4 o;
    o.x = f2h(v.x); o.y = f2h(v.y); o.z = f2h(v.z); o.w = f2h(v.w);
    ((ushort4*)out)[i] = o;
  }
}

// ---------- M[512x512] -> Mt fp16 (Mt[e][d] = M[d][e]) ----------
__global__ void k_mt(const float* __restrict__ M, u16* __restrict__ Mt) {
  __shared__ float t[32][33];
  int bx = blockIdx.x * 32;  // e range
  int by = blockIdx.y * 32;  // d range
  for (int r = 0; r < 32; r += 8)
    t[threadIdx.y + r][threadIdx.x] = M[(size_t)(by + threadIdx.y + r) * DD + bx + threadIdx.x];
  __syncthreads();
  for (int r = 0; r < 32; r += 8)
    Mt[(size_t)(bx + threadIdx.y + r) * DD + by + threadIdx.x] = f2h(t[threadIdx.x][threadIdx.y + r]);
}

// ---------- eT'[b][d][m] = fp16( e[b][m][d] * 2048 / colsum[b][m] ) ----------
__global__ void k_et(const float* __restrict__ e, const float* __restrict__ cs,
                     u16* __restrict__ eT) {
  __shared__ float t[32][33];
  int b = blockIdx.z;
  int m0 = blockIdx.y * 32, d0 = blockIdx.x * 32;
  const float* eb = e + (size_t)b * NE * DD;
  const float* csb = cs + (size_t)b * NE;
  for (int r = 0; r < 32; r += 8) {
    int m = m0 + threadIdx.y + r;
    t[threadIdx.y + r][threadIdx.x] =
        eb[(size_t)m * DD + d0 + threadIdx.x] * (2048.0f / csb[m]);
  }
  __syncthreads();
  u16* eTb = eT + (size_t)b * DD * NE;
  for (int r = 0; r < 32; r += 8) {
    int d = d0 + threadIdx.y + r;
    eTb[(size_t)d * NE + m0 + threadIdx.x] = f2h(t[threadIdx.x][threadIdx.y + r]);
  }
}

// ---------- generic fp16 gemm_bt: C = A[MxK] * Bt[NxK]^T ----------
// 128x128 tile, BK=32, 4 waves (2x2), each wave 64x64 = 4x4 frags of 16x16x32.
// EPI: 0 = store fp16; 1 = exp(sigmoid(x)) store fp16 + colsum atomics;
//      2 = store f32 scaled by 1/2048
template<int EPI>
__global__ __launch_bounds__(256, 2) void k_gemm(
    const u16* __restrict__ A, const u16* __restrict__ Bt, void* __restrict__ Cp,
    int Ndim, int K, long long sAb, long long sBb, long long sCb,
    float* __restrict__ colsum, int csld)
{
  const int tid = threadIdx.x;
  const int lane = tid & 63;
  const int wid = tid >> 6;
  const int wr = wid >> 1, wc = wid & 1;
  const int bz = blockIdx.z;
  const int row0 = blockIdx.y * 128;
  const int col0 = blockIdx.x * 128;

  const u16* Ab = A + (long long)bz * sAb;
  const u16* Bb = Bt + (long long)bz * sBb;

  __shared__ u16 As[2][128 * 32];
  __shared__ u16 Bs[2][128 * 32];

  f32x4 acc[4][4] = {};

  const int rA = lane & 15;
  const int kq = (lane >> 4) * 8;

  const int nk = K >> 5;
  int cur = 0;

  auto stage = [&](int buf, int kt) {
    const int k0 = kt * 32;
#pragma unroll
    for (int c = 0; c < 2; ++c) {
      int q = c * 256 + tid;
      int r = q >> 2, col = (q & 3) * 8;
      // LDS dest: wave-uniform base; HW adds lane*16
      gload_lds16(Ab + (long long)(row0 + r) * K + k0 + col,
                  (char*)(&As[buf][0]) + (c * 256 + wid * 64) * 16);
      gload_lds16(Bb + (long long)(col0 + r) * K + k0 + col,
                  (char*)(&Bs[buf][0]) + (c * 256 + wid * 64) * 16);
    }
  };

  stage(0, 0);
  for (int kt = 0; kt < nk; ++kt) {
    __syncthreads();                      // staging of `cur` complete; prev readers done
    if (kt + 1 < nk) stage(cur ^ 1, kt + 1);
    const u16* as = &As[cur][0];
    const u16* bs = &Bs[cur][0];
    f16x8 af[4], bfr[4];
#pragma unroll
    for (int m = 0; m < 4; ++m)
      af[m] = *(const f16x8*)(as + (wr * 64 + m * 16 + rA) * 32 + kq);
#pragma unroll
    for (int n = 0; n < 4; ++n)
      bfr[n] = *(const f16x8*)(bs + (wc * 64 + n * 16 + rA) * 32 + kq);
#pragma unroll
    for (int m = 0; m < 4; ++m)
#pragma unroll
      for (int n = 0; n < 4; ++n)
        acc[m][n] = __builtin_amdgcn_mfma_f32_16x16x32_f16(af[m], bfr[n], acc[m][n], 0, 0, 0);
    cur ^= 1;
  }

  // C/D frag layout: col = lane&15, row = (lane>>4)*4 + j   [verified m89/m91]
  if constexpr (EPI == 0) {
    u16* C = (u16*)Cp + (long long)bz * sCb;
#pragma unroll
    for (int m = 0; m < 4; ++m)
#pragma unroll
      for (int n = 0; n < 4; ++n)
#pragma unroll
        for (int j = 0; j < 4; ++j) {
          int row = row0 + wr * 64 + m * 16 + (lane >> 4) * 4 + j;
          int col = col0 + wc * 64 + n * 16 + (lane & 15);
          C[(long long)row * Ndim + col] = f2h(acc[m][n][j]);
        }
  } else if constexpr (EPI == 1) {
    u16* C = (u16*)Cp + (long long)bz * sCb;
    float csum[4] = {0.f, 0.f, 0.f, 0.f};
#pragma unroll
    for (int m = 0; m < 4; ++m)
#pragma unroll
      for (int n = 0; n < 4; ++n)
#pragma unroll
        for (int j = 0; j < 4; ++j) {
          float x = acc[m][n][j];
          float s = 1.f / (1.f + __expf(-x));   // sigmoid; saturates safely
          float v = __expf(s);                  // in (1, e)
          int row = row0 + wr * 64 + m * 16 + (lane >> 4) * 4 + j;
          int col = col0 + wc * 64 + n * 16 + (lane & 15);
          C[(long long)row * Ndim + col] = f2h(v);
          csum[n] += v;
        }
#pragma unroll
    for (int n = 0; n < 4; ++n) {
      float v = csum[n];
      v += __shfl_xor(v, 16, 64);
      v += __shfl_xor(v, 32, 64);
      if ((lane >> 4) == 0)
        atomicAdd(&colsum[(long long)bz * csld + col0 + wc * 64 + n * 16 + (lane & 15)], v);
    }
  } else {
    float* C = (float*)Cp + (long long)bz * sCb;
#pragma unroll
    for (int m = 0; m < 4; ++m)
#pragma unroll
      for (int n = 0; n < 4; ++n)
#pragma unroll
        for (int j = 0; j < 4; ++j) {
          int row = row0 + wr * 64 + m * 16 + (lane >> 4) * 4 + j;
          int col = col0 + wc * 64 + n * 16 + (lane & 15);
          C[(long long)row * Ndim + col] = acc[m][n][j] * (1.0f / 2048.0f);
        }
  }
}

// ---------- launch ----------
// ws layout (bytes):
//   S      @ 0          : 16*2048*2048*2 = 134217728
//   zM     @ 134217728  : 16*2048*512*2  =  33554432
//   zH/eT  @ 167772160  :                  33554432   (z fp16; reused as eT after gemm1)
//   eH     @ 201326592  :                  33554432
//   Mt     @ 234881024  :                    524288
//   colsum @ 235405312  : 16*2048*4      =    131072
//   total 235536384 (~225 MiB)
extern "C" void kernel_launch(void* const* d_in, const int* in_sizes, int n_in,
                              void* d_out, int out_size, void* d_ws, size_t ws_size,
                              hipStream_t stream) {
  const float* z = (const float*)d_in[0];
  const float* e = (const float*)d_in[1];
  const float* M = (const float*)d_in[2];
  float* out = (float*)d_out;
  char* ws = (char*)d_ws;

  u16* S    = (u16*)(ws + 0LL);
  u16* zM   = (u16*)(ws + 134217728LL);
  u16* zH   = (u16*)(ws + 167772160LL);
  u16* eH   = (u16*)(ws + 201326592LL);
  u16* Mt   = (u16*)(ws + 234881024LL);
  float* cs = (float*)(ws + 235405312LL);

  hipMemsetAsync(cs, 0, (size_t)BB * NE * sizeof(float), stream);

  k_cvt<<<4096, 256, 0, stream>>>(z, zH, BB * NZ * DD / 4);
  k_cvt<<<4096, 256, 0, stream>>>(e, eH, BB * NE * DD / 4);
  k_mt<<<dim3(16, 16), dim3(32, 8), 0, stream>>>(M, Mt);

  // zM[32768 x 512] = zH @ Mt^T   (batch folded into rows)
  k_gemm<0><<<dim3(DD / 128, (BB * NZ) / 128, 1), 256, 0, stream>>>(
      zH, Mt, zM, DD, DD, 0LL, 0LL, 0LL, nullptr, 0);

  // S[b] = exp(sigmoid(zM[b] @ eH[b]^T)) ; colsum[b][m] += column sums
  k_gemm<1><<<dim3(NE / 128, NZ / 128, BB), 256, 0, stream>>>(
      zM, eH, S, NE, DD,
      (long long)NZ * DD, (long long)NE * DD, (long long)NZ * NE, cs, NE);

  // eT'[b][d][m] = fp16(e[b][m][d] * 2048 / colsum[b][m])   (reuses zH region)
  u16* eT = zH;
  k_et<<<dim3(DD / 32, NE / 32, BB), dim3(32, 8), 0, stream>>>(e, cs, eT);

  // out[b] = (S[b] @ eT[b]^T) / 2048   (f32 store)
  k_gemm<2><<<dim3(DD / 128, NZ / 128, BB), 256, 0, stream>>>(
      S, eT, out, DD, NE,
      (long long)NZ * NE, (long long)DD * NE, (long long)NZ * DD, nullptr, 0);
}

// Round 3
// 326.328 us; speedup vs baseline: 1.0177x; 1.0177x over previous
//
#include <hip/hip_runtime.h>
#include <hip/hip_bf16.h>
#include <stdint.h>

#define BB 16
#define NZ 2048
#define NE 2048
#define DD 512

typedef unsigned short u16;
typedef __attribute__((ext_vector_type(8))) _Float16 f16x8;  // 8 fp16 = 4 VGPR
typedef __attribute__((ext_vector_type(4))) float f32x4;

// ---------- helpers ----------
__device__ __forceinline__ u16 f2h(float f) {
  _Float16 h = (_Float16)f;                 // v_cvt_f16_f32, RNE
  return __builtin_bit_cast(u16, h);
}

__device__ __forceinline__ void gload_lds16(const void* g, void* l) {
  auto gp = (const __attribute__((address_space(1))) uint32_t*)g;
  auto lp = (__attribute__((address_space(3))) uint32_t*)l;
  __builtin_amdgcn_global_load_lds(gp, lp, 16, 0, 0);
}

#define FENCE() asm volatile("" ::: "memory")
#define BARRIER() do { FENCE(); __builtin_amdgcn_s_barrier(); FENCE(); } while (0)
#define WAIT_LGKM0() do { asm volatile("s_waitcnt lgkmcnt(0)" ::: "memory"); \
                          __builtin_amdgcn_sched_barrier(0); } while (0)
#define WAIT_VM(n) asm volatile("s_waitcnt vmcnt(" #n ")" ::: "memory")

// ---------- f32 -> fp16 bulk convert ----------
__global__ void k_cvt(const float* __restrict__ in, u16* __restrict__ out, int n4) {
  int i = blockIdx.x * blockDim.x + threadIdx.x;
  int stride = gridDim.x * blockDim.x;
  for (; i < n4; i += stride) {
    float4 v = ((const float4*)in)[i];
    ushort4 o;
    o.x = f2h(v.x); o.y = f2h(v.y); o.z = f2h(v.z); o.w = f2h(v.w);
    ((ushort4*)out)[i] = o;
  }
}

// ---------- M[512x512] -> Mt fp16 (Mt[e][d] = M[d][e]) ----------
__global__ void k_mt(const float* __restrict__ M, u16* __restrict__ Mt) {
  __shared__ float t[32][33];
  int bx = blockIdx.x * 32;  // e range
  int by = blockIdx.y * 32;  // d range
  for (int r = 0; r < 32; r += 8)
    t[threadIdx.y + r][threadIdx.x] = M[(size_t)(by + threadIdx.y + r) * DD + bx + threadIdx.x];
  __syncthreads();
  for (int r = 0; r < 32; r += 8)
    Mt[(size_t)(bx + threadIdx.y + r) * DD + by + threadIdx.x] = f2h(t[threadIdx.x][threadIdx.y + r]);
}

// ---------- eT'[b][d][m] = fp16( e[b][m][d] * 2048 / colsum[b][m] ) ----------
__global__ void k_et(const float* __restrict__ e, const float* __restrict__ cs,
                     u16* __restrict__ eT) {
  __shared__ float t[32][33];
  int b = blockIdx.z;
  int m0 = blockIdx.y * 32, d0 = blockIdx.x * 32;
  const float* eb = e + (size_t)b * NE * DD;
  const float* csb = cs + (size_t)b * NE;
  for (int r = 0; r < 32; r += 8) {
    int m = m0 + threadIdx.y + r;
    t[threadIdx.y + r][threadIdx.x] =
        eb[(size_t)m * DD + d0 + threadIdx.x] * (2048.0f / csb[m]);
  }
  __syncthreads();
  u16* eTb = eT + (size_t)b * DD * NE;
  for (int r = 0; r < 32; r += 8) {
    int d = d0 + threadIdx.y + r;
    eTb[(size_t)d * NE + m0 + threadIdx.x] = f2h(t[threadIdx.x][threadIdx.y + r]);
  }
}

// ---------- 256x256 tile, BK=64, 8-wave deep-pipelined fp16 gemm_bt ----------
// C = A[Mx K] * Bt[N x K]^T.  512 threads = 8 waves (2M x 4N), per-wave 128x64.
// LDS (dynamic, 128 KiB): A[2][2048 chunks of 16B], B[2][...] in FRAGMENT-MAJOR
// order: chunk(r, c8) -> ((c8>>2)*16 + (r>>4))*64 + (c8&3)*16 + (r&15).
// ds_read of any MFMA fragment = uniform base + lane*16 (conflict-free);
// global_load_lds writes linearly with the per-lane SOURCE address permuted.
// Schedule per K-tile: 4 phases x {ds_read, [stage], bar, lgkmcnt0, 16 MFMA, bar};
// full next-tile stage (8 loads) issued at P0; vmcnt(8) at P1-end, vmcnt(4) at
// P3-end (counted, never 0 in steady state).
// EPI: 0 = store fp16; 1 = exp(sigmoid(x)) store fp16 + colsum atomics;
//      2 = store f32 scaled by 1/2048
template<int EPI, int KDIM>
__global__ __launch_bounds__(512, 2) void k_gemm(
    const u16* __restrict__ A, const u16* __restrict__ Bt, void* __restrict__ Cp,
    int Ndim, long long sAb, long long sBb, long long sCb,
    float* __restrict__ colsum, int csld)
{
  extern __shared__ char lds[];
  constexpr int NT = KDIM / 64;

  // bijective XCD-aware swizzle (nwg % 8 == 0 for all our launches)
  const int gx = gridDim.x, gy = gridDim.y;
  const int nwg = gx * gy * gridDim.z;
  const int hid = blockIdx.x + gx * (blockIdx.y + gy * blockIdx.z);
  const int logical = (hid & 7) * (nwg >> 3) + (hid >> 3);
  const int bx = logical % gx;
  const int rem0 = logical / gx;
  const int by = rem0 % gy;
  const int bz = rem0 / gy;

  const int tid = threadIdx.x;
  const int lane = tid & 63;
  const int wid = tid >> 6;
  const int wr = wid >> 2;   // 0..1
  const int wc = wid & 3;    // 0..3

  const int row0 = by * 256;
  const int col0 = bx * 256;

  const u16* Ab = A + (long long)bz * sAb;
  const u16* Bb = Bt + (long long)bz * sBb;

  // staging source coords (per call c = 0..3; calls 0,1 are ks=0, 2,3 are ks=1)
  const u16* srcA[4]; const u16* srcB[4];
#pragma unroll
  for (int c = 0; c < 4; ++c) {
    int idx = c * 512 + tid;
    int ks = idx >> 10, rm = idx & 1023;
    int mf = rm >> 6, q = (rm >> 4) & 3, p = rm & 15;
    int r = mf * 16 + p, c8 = ks * 4 + q;
    srcA[c] = Ab + (long long)(row0 + r) * KDIM + c8 * 8;
    srcB[c] = Bb + (long long)(col0 + r) * KDIM + c8 * 8;
  }

  // issue order: A0,B0,A1,B1 (ks0) then A2,B2,A3,B3 (ks1) -> first 4 = ks0
  auto stage = [&](int buf, int k0) {
#pragma unroll
    for (int c = 0; c < 4; ++c) {
      gload_lds16(srcA[c] + k0, lds + buf * 32768 + (c * 512 + wid * 64) * 16);
      gload_lds16(srcB[c] + k0, lds + 65536 + buf * 32768 + (c * 512 + wid * 64) * 16);
    }
  };

  auto ldA = [&](int buf, int ks, int m) -> f16x8 {
    return *(const f16x8*)(lds + buf * 32768 +
                           ((ks * 16 + wr * 8 + m) * 64 + lane) * 16);
  };
  auto ldB = [&](int buf, int ks, int n) -> f16x8 {
    return *(const f16x8*)(lds + 65536 + buf * 32768 +
                           ((ks * 16 + wc * 4 + n) * 64 + lane) * 16);
  };

  f32x4 acc[8][4] = {};
  f16x8 af[4], bf[4];

  stage(0, 0);
  WAIT_VM(4);           // ks0 half of tile 0 landed (own wave); barrier covers all
  BARRIER();

  for (int t = 0; t < NT; ++t) {
    const int buf = t & 1;
    // ---- P0: ks0, m0-3 ----
#pragma unroll
    for (int m = 0; m < 4; ++m) af[m] = ldA(buf, 0, m);
#pragma unroll
    for (int n = 0; n < 4; ++n) bf[n] = ldB(buf, 0, n);
    if (t + 1 < NT) stage(buf ^ 1, (t + 1) * 64);
    BARRIER();
    WAIT_LGKM0();
    __builtin_amdgcn_s_setprio(1);
#pragma unroll
    for (int m = 0; m < 4; ++m)
#pragma unroll
      for (int n = 0; n < 4; ++n)
        acc[m][n] = __builtin_amdgcn_mfma_f32_16x16x32_f16(af[m], bf[n], acc[m][n], 0, 0, 0);
    __builtin_amdgcn_s_setprio(0);
    BARRIER();
    // ---- P1: ks0, m4-7 (reuses bf) ----
#pragma unroll
    for (int m = 0; m < 4; ++m) af[m] = ldA(buf, 0, 4 + m);
    BARRIER();
    WAIT_LGKM0();
    __builtin_amdgcn_s_setprio(1);
#pragma unroll
    for (int m = 0; m < 4; ++m)
#pragma unroll
      for (int n = 0; n < 4; ++n)
        acc[4 + m][n] = __builtin_amdgcn_mfma_f32_16x16x32_f16(af[m], bf[n], acc[4 + m][n], 0, 0, 0);
    __builtin_amdgcn_s_setprio(0);
    // this tile's ks1 half was staged one tile ago; 8 loads (next tile) trail it
    if (t + 1 < NT) { WAIT_VM(8); } else { WAIT_VM(0); }
    BARRIER();
    // ---- P2: ks1, m0-3 ----
#pragma unroll
    for (int m = 0; m < 4; ++m) af[m] = ldA(buf, 1, m);
#pragma unroll
    for (int n = 0; n < 4; ++n) bf[n] = ldB(buf, 1, n);
    BARRIER();
    WAIT_LGKM0();
    __builtin_amdgcn_s_setprio(1);
#pragma unroll
    for (int m = 0; m < 4; ++m)
#pragma unroll
      for (int n = 0; n < 4; ++n)
        acc[m][n] = __builtin_amdgcn_mfma_f32_16x16x32_f16(af[m], bf[n], acc[m][n], 0, 0, 0);
    __builtin_amdgcn_s_setprio(0);
    BARRIER();
    // ---- P3: ks1, m4-7 ----
#pragma unroll
    for (int m = 0; m < 4; ++m) af[m] = ldA(buf, 1, 4 + m);
    BARRIER();
    WAIT_LGKM0();
    __builtin_amdgcn_s_setprio(1);
#pragma unroll
    for (int m = 0; m < 4; ++m)
#pragma unroll
      for (int n = 0; n < 4; ++n)
        acc[4 + m][n] = __builtin_amdgcn_mfma_f32_16x16x32_f16(af[m], bf[n], acc[4 + m][n], 0, 0, 0);
    __builtin_amdgcn_s_setprio(0);
    // next tile's ks0 half (first 4 of the 8 staged at P0) must land; 4 trail
    if (t + 1 < NT) { WAIT_VM(4); }
    BARRIER();
  }

  // C/D frag layout: col = lane&15, row = (lane>>4)*4 + j
  const int rr = (lane >> 4) * 4;
  const int cc = lane & 15;
  if constexpr (EPI == 0) {
    u16* C = (u16*)Cp + (long long)bz * sCb;
#pragma unroll
    for (int m = 0; m < 8; ++m)
#pragma unroll
      for (int n = 0; n < 4; ++n)
#pragma unroll
        for (int j = 0; j < 4; ++j) {
          int row = row0 + wr * 128 + m * 16 + rr + j;
          int col = col0 + wc * 64 + n * 16 + cc;
          C[(long long)row * Ndim + col] = f2h(acc[m][n][j]);
        }
  } else if constexpr (EPI == 1) {
    u16* C = (u16*)Cp + (long long)bz * sCb;
    float csum[4] = {0.f, 0.f, 0.f, 0.f};
#pragma unroll
    for (int m = 0; m < 8; ++m)
#pragma unroll
      for (int n = 0; n < 4; ++n)
#pragma unroll
        for (int j = 0; j < 4; ++j) {
          float x = acc[m][n][j];
          float s = 1.f / (1.f + __expf(-x));   // sigmoid
          float v = __expf(s);                  // in (1, e)
          int row = row0 + wr * 128 + m * 16 + rr + j;
          int col = col0 + wc * 64 + n * 16 + cc;
          C[(long long)row * Ndim + col] = f2h(v);
          csum[n] += v;
        }
#pragma unroll
    for (int n = 0; n < 4; ++n) {
      float v = csum[n];
      v += __shfl_xor(v, 16, 64);
      v += __shfl_xor(v, 32, 64);
      if ((lane >> 4) == 0)
        atomicAdd(&colsum[(long long)bz * csld + col0 + wc * 64 + n * 16 + cc], v);
    }
  } else {
    float* C = (float*)Cp + (long long)bz * sCb;
#pragma unroll
    for (int m = 0; m < 8; ++m)
#pragma unroll
      for (int n = 0; n < 4; ++n)
#pragma unroll
        for (int j = 0; j < 4; ++j) {
          int row = row0 + wr * 128 + m * 16 + rr + j;
          int col = col0 + wc * 64 + n * 16 + cc;
          C[(long long)row * Ndim + col] = acc[m][n][j] * (1.0f / 2048.0f);
        }
  }
}

// ---------- launch ----------
// ws layout (bytes):
//   S      @ 0          : 16*2048*2048*2 = 134217728
//   zM     @ 134217728  : 16*2048*512*2  =  33554432
//   zH/eT  @ 167772160  :                  33554432   (z fp16; reused as eT)
//   eH     @ 201326592  :                  33554432
//   Mt     @ 234881024  :                    524288
//   colsum @ 235405312  : 16*2048*4      =    131072
extern "C" void kernel_launch(void* const* d_in, const int* in_sizes, int n_in,
                              void* d_out, int out_size, void* d_ws, size_t ws_size,
                              hipStream_t stream) {
  const float* z = (const float*)d_in[0];
  const float* e = (const float*)d_in[1];
  const float* M = (const float*)d_in[2];
  float* out = (float*)d_out;
  char* ws = (char*)d_ws;

  u16* S    = (u16*)(ws + 0LL);
  u16* zM   = (u16*)(ws + 134217728LL);
  u16* zH   = (u16*)(ws + 167772160LL);
  u16* eH   = (u16*)(ws + 201326592LL);
  u16* Mt   = (u16*)(ws + 234881024LL);
  float* cs = (float*)(ws + 235405312LL);

  // allow 128 KiB dynamic LDS (idempotent; persists from the first,
  // uncaptured, correctness call)
  (void)hipFuncSetAttribute(reinterpret_cast<const void*>(&k_gemm<0, 512>),
                            hipFuncAttributeMaxDynamicSharedMemorySize, 131072);
  (void)hipFuncSetAttribute(reinterpret_cast<const void*>(&k_gemm<1, 512>),
                            hipFuncAttributeMaxDynamicSharedMemorySize, 131072);
  (void)hipFuncSetAttribute(reinterpret_cast<const void*>(&k_gemm<2, 2048>),
                            hipFuncAttributeMaxDynamicSharedMemorySize, 131072);

  hipMemsetAsync(cs, 0, (size_t)BB * NE * sizeof(float), stream);

  k_cvt<<<4096, 256, 0, stream>>>(z, zH, BB * NZ * DD / 4);
  k_cvt<<<4096, 256, 0, stream>>>(e, eH, BB * NE * DD / 4);
  k_mt<<<dim3(16, 16), dim3(32, 8), 0, stream>>>(M, Mt);

  // zM[32768 x 512] = zH @ Mt^T   (batch folded into rows); 256 blocks
  k_gemm<0, 512><<<dim3(DD / 256, (BB * NZ) / 256, 1), 512, 131072, stream>>>(
      zH, Mt, zM, DD, 0LL, 0LL, 0LL, nullptr, 0);

  // S[b] = exp(sigmoid(zM[b] @ eH[b]^T)) ; colsum atomics; 1024 blocks
  k_gemm<1, 512><<<dim3(NE / 256, NZ / 256, BB), 512, 131072, stream>>>(
      zM, eH, S, NE,
      (long long)NZ * DD, (long long)NE * DD, (long long)NZ * NE, cs, NE);

  // eT'[b][d][m] = fp16(e[b][m][d] * 2048 / colsum[b][m])   (reuses zH region)
  u16* eT = zH;
  k_et<<<dim3(DD / 32, NE / 32, BB), dim3(32, 8), 0, stream>>>(e, cs, eT);

  // out[b] = (S[b] @ eT[b]^T) / 2048 ; 256 blocks
  k_gemm<2, 2048><<<dim3(DD / 256, NZ / 256, BB), 512, 131072, stream>>>(
      S, eT, out, DD,
      (long long)NZ * NE, (long long)DD * NE, (long long)NZ * DD, nullptr, 0);
}

// Round 4
// 279.794 us; speedup vs baseline: 1.1870x; 1.1663x over previous
//
#include <hip/hip_runtime.h>
#include <hip/hip_bf16.h>
#include <stdint.h>

#define BB 16
#define NZ 2048
#define NE 2048
#define DD 512

typedef unsigned short u16;
typedef __attribute__((ext_vector_type(8))) _Float16 f16x8;  // 8 fp16 = 4 VGPR
typedef __attribute__((ext_vector_type(4))) float f32x4;

// ---------- helpers ----------
__device__ __forceinline__ u16 f2h(float f) {
  _Float16 h = (_Float16)f;                 // v_cvt_f16_f32, RNE
  return __builtin_bit_cast(u16, h);
}

__device__ __forceinline__ float h2f(u16 h) {
  return (float)__builtin_bit_cast(_Float16, h);
}

__device__ __forceinline__ void gload_lds16(const void* g, void* l) {
  auto gp = (const __attribute__((address_space(1))) uint32_t*)g;
  auto lp = (__attribute__((address_space(3))) uint32_t*)l;
  __builtin_amdgcn_global_load_lds(gp, lp, 16, 0, 0);
}

#define FENCE() asm volatile("" ::: "memory")
#define BARRIER() do { FENCE(); __builtin_amdgcn_s_barrier(); FENCE(); } while (0)
#define WAIT_LGKM0() asm volatile("s_waitcnt lgkmcnt(0)" ::: "memory")
#define WAIT_VM(n) asm volatile("s_waitcnt vmcnt(" #n ")" ::: "memory")

// ---------- f32 -> fp16 bulk convert ----------
__global__ void k_cvt(const float* __restrict__ in, u16* __restrict__ out, int n4) {
  int i = blockIdx.x * blockDim.x + threadIdx.x;
  int stride = gridDim.x * blockDim.x;
  for (; i < n4; i += stride) {
    float4 v = ((const float4*)in)[i];
    ushort4 o;
    o.x = f2h(v.x); o.y = f2h(v.y); o.z = f2h(v.z); o.w = f2h(v.w);
    ((ushort4*)out)[i] = o;
  }
}

// ---------- M[512x512] -> Mt fp16 (Mt[e][d] = M[d][e]) ----------
__global__ void k_mt(const float* __restrict__ M, u16* __restrict__ Mt) {
  __shared__ float t[32][33];
  int bx = blockIdx.x * 32;  // e range
  int by = blockIdx.y * 32;  // d range
  for (int r = 0; r < 32; r += 8)
    t[threadIdx.y + r][threadIdx.x] = M[(size_t)(by + threadIdx.y + r) * DD + bx + threadIdx.x];
  __syncthreads();
  for (int r = 0; r < 32; r += 8)
    Mt[(size_t)(bx + threadIdx.y + r) * DD + by + threadIdx.x] = f2h(t[threadIdx.x][threadIdx.y + r]);
}

// ---------- eT'[b][d][m] = fp16( eH[b][m][d] * 2048 / colsum[b][m] ) ----------
// reads the fp16 eH (32 MB) instead of f32 e (128 MB)
__global__ void k_et(const u16* __restrict__ eH, const float* __restrict__ cs,
                     u16* __restrict__ eT) {
  __shared__ float t[32][33];
  int b = blockIdx.z;
  int m0 = blockIdx.y * 32, d0 = blockIdx.x * 32;
  const u16* eb = eH + (size_t)b * NE * DD;
  const float* csb = cs + (size_t)b * NE;
  for (int r = 0; r < 32; r += 8) {
    int m = m0 + threadIdx.y + r;
    t[threadIdx.y + r][threadIdx.x] =
        h2f(eb[(size_t)m * DD + d0 + threadIdx.x]) * (2048.0f / csb[m]);
  }
  __syncthreads();
  u16* eTb = eT + (size_t)b * DD * NE;
  for (int r = 0; r < 32; r += 8) {
    int d = d0 + threadIdx.y + r;
    eTb[(size_t)d * NE + m0 + threadIdx.x] = f2h(t[threadIdx.x][threadIdx.y + r]);
  }
}

// ---------- 256x256 tile, BK=64, 8-wave deep-pipelined fp16 gemm_bt ----------
// C = A[M x K] * Bt[N x K]^T.  512 threads = 8 waves (2M x 4N), per-wave 128x64.
// LDS (dynamic, 128 KiB): fragment-major chunks; ds_read of any MFMA fragment
// = uniform base + lane*16 (conflict-free); global_load_lds writes linearly
// with the per-lane SOURCE address permuted (both-sides rule).
// Per K-tile: 4 phases, each {ds_read frags; 2 x global_load_lds (spread);
// barrier; lgkmcnt(0); setprio(1); 16 MFMA; setprio(0); [vmcnt(4)]; barrier}.
// vmcnt(4) at P1-end (tile's ks1 ready) and P3-end (next tile's ks0 ready);
// never 0 in steady state.  NO sched_barrier (m141: order-pinning -43%).
// EPI: 0 = store fp16; 1 = exp(sigmoid(x)) store fp16 + colsum atomics;
//      2 = store f32 scaled by 1/2048
template<int EPI, int KDIM>
__global__ __launch_bounds__(512, 2) void k_gemm(
    const u16* __restrict__ A, const u16* __restrict__ Bt, void* __restrict__ Cp,
    int Ndim, long long sAb, long long sBb, long long sCb,
    float* __restrict__ colsum, int csld)
{
  extern __shared__ char lds[];
  constexpr int NT = KDIM / 64;

  // bijective XCD-aware swizzle (nwg % 8 == 0 for all our launches)
  const int gx = gridDim.x, gy = gridDim.y;
  const int nwg = gx * gy * gridDim.z;
  const int hid = blockIdx.x + gx * (blockIdx.y + gy * blockIdx.z);
  const int logical = (hid & 7) * (nwg >> 3) + (hid >> 3);
  const int bx = logical % gx;
  const int rem0 = logical / gx;
  const int by = rem0 % gy;
  const int bz = rem0 / gy;

  const int tid = threadIdx.x;
  const int lane = tid & 63;
  const int wid = tid >> 6;
  const int wr = wid >> 2;   // 0..1
  const int wc = wid & 3;    // 0..3

  const int row0 = by * 256;
  const int col0 = bx * 256;

  const u16* Ab = A + (long long)bz * sAb;
  const u16* Bb = Bt + (long long)bz * sBb;

  // staging source coords (call c = 0..3; c=0,1 are ks0, c=2,3 are ks1)
  const u16* srcA[4]; const u16* srcB[4];
#pragma unroll
  for (int c = 0; c < 4; ++c) {
    int idx = c * 512 + tid;
    int ks = idx >> 10, rm = idx & 1023;
    int mf = rm >> 6, q = (rm >> 4) & 3, p = rm & 15;
    int r = mf * 16 + p, c8 = ks * 4 + q;
    srcA[c] = Ab + (long long)(row0 + r) * KDIM + c8 * 8;
    srcB[c] = Bb + (long long)(col0 + r) * KDIM + c8 * 8;
  }

  auto stageA = [&](int buf, int k0, int c0) {
#pragma unroll
    for (int c = c0; c < c0 + 2; ++c)
      gload_lds16(srcA[c] + k0, lds + buf * 32768 + (c * 512 + wid * 64) * 16);
  };
  auto stageB = [&](int buf, int k0, int c0) {
#pragma unroll
    for (int c = c0; c < c0 + 2; ++c)
      gload_lds16(srcB[c] + k0, lds + 65536 + buf * 32768 + (c * 512 + wid * 64) * 16);
  };

  auto ldA = [&](int buf, int ks, int m) -> f16x8 {
    return *(const f16x8*)(lds + buf * 32768 +
                           ((ks * 16 + wr * 8 + m) * 64 + lane) * 16);
  };
  auto ldB = [&](int buf, int ks, int n) -> f16x8 {
    return *(const f16x8*)(lds + 65536 + buf * 32768 +
                           ((ks * 16 + wc * 4 + n) * 64 + lane) * 16);
  };

  f32x4 acc[8][4] = {};
  f16x8 af[4], bf[4];

  // prologue: stage tile 0 fully; wait for its ks0 half (first 4 loads)
  stageA(0, 0, 0); stageB(0, 0, 0);   // A-ks0, B-ks0
  stageA(0, 0, 2); stageB(0, 0, 2);   // A-ks1, B-ks1
  WAIT_VM(4);
  BARRIER();

  for (int t = 0; t < NT; ++t) {
    const int buf = t & 1;
    const bool pf = (t + 1 < NT);
    const int nk0 = (t + 1) * 64;
    // ---- P0: ks0, m0-3 ----
#pragma unroll
    for (int m = 0; m < 4; ++m) af[m] = ldA(buf, 0, m);
#pragma unroll
    for (int n = 0; n < 4; ++n) bf[n] = ldB(buf, 0, n);
    if (pf) stageA(buf ^ 1, nk0, 0);
    BARRIER();
    WAIT_LGKM0();
    __builtin_amdgcn_s_setprio(1);
#pragma unroll
    for (int m = 0; m < 4; ++m)
#pragma unroll
      for (int n = 0; n < 4; ++n)
        acc[m][n] = __builtin_amdgcn_mfma_f32_16x16x32_f16(af[m], bf[n], acc[m][n], 0, 0, 0);
    __builtin_amdgcn_s_setprio(0);
    BARRIER();
    // ---- P1: ks0, m4-7 (reuses bf) ----
#pragma unroll
    for (int m = 0; m < 4; ++m) af[m] = ldA(buf, 0, 4 + m);
    if (pf) stageB(buf ^ 1, nk0, 0);
    BARRIER();
    WAIT_LGKM0();
    __builtin_amdgcn_s_setprio(1);
#pragma unroll
    for (int m = 0; m < 4; ++m)
#pragma unroll
      for (int n = 0; n < 4; ++n)
        acc[4 + m][n] = __builtin_amdgcn_mfma_f32_16x16x32_f16(af[m], bf[n], acc[4 + m][n], 0, 0, 0);
    __builtin_amdgcn_s_setprio(0);
    // this tile's ks1 (4 oldest outstanding loads) must have landed
    if (pf) { WAIT_VM(4); } else { WAIT_VM(0); }
    BARRIER();
    // ---- P2: ks1, m0-3 ----
#pragma unroll
    for (int m = 0; m < 4; ++m) af[m] = ldA(buf, 1, m);
#pragma unroll
    for (int n = 0; n < 4; ++n) bf[n] = ldB(buf, 1, n);
    if (pf) stageA(buf ^ 1, nk0, 2);
    BARRIER();
    WAIT_LGKM0();
    __builtin_amdgcn_s_setprio(1);
#pragma unroll
    for (int m = 0; m < 4; ++m)
#pragma unroll
      for (int n = 0; n < 4; ++n)
        acc[m][n] = __builtin_amdgcn_mfma_f32_16x16x32_f16(af[m], bf[n], acc[m][n], 0, 0, 0);
    __builtin_amdgcn_s_setprio(0);
    BARRIER();
    // ---- P3: ks1, m4-7 ----
#pragma unroll
    for (int m = 0; m < 4; ++m) af[m] = ldA(buf, 1, 4 + m);
    if (pf) stageB(buf ^ 1, nk0, 2);
    BARRIER();
    WAIT_LGKM0();
    __builtin_amdgcn_s_setprio(1);
#pragma unroll
    for (int m = 0; m < 4; ++m)
#pragma unroll
      for (int n = 0; n < 4; ++n)
        acc[4 + m][n] = __builtin_amdgcn_mfma_f32_16x16x32_f16(af[m], bf[n], acc[4 + m][n], 0, 0, 0);
    __builtin_amdgcn_s_setprio(0);
    // next tile's ks0 (4 oldest of the 8 outstanding) must have landed
    if (pf) { WAIT_VM(4); }
    BARRIER();
  }

  // C/D frag layout: col = lane&15, row = (lane>>4)*4 + j
  const int rr = (lane >> 4) * 4;
  const int cc = lane & 15;
  if constexpr (EPI == 0) {
    u16* C = (u16*)Cp + (long long)bz * sCb;
#pragma unroll
    for (int m = 0; m < 8; ++m)
#pragma unroll
      for (int n = 0; n < 4; ++n)
#pragma unroll
        for (int j = 0; j < 4; ++j) {
          int row = row0 + wr * 128 + m * 16 + rr + j;
          int col = col0 + wc * 64 + n * 16 + cc;
          C[(long long)row * Ndim + col] = f2h(acc[m][n][j]);
        }
  } else if constexpr (EPI == 1) {
    u16* C = (u16*)Cp + (long long)bz * sCb;
    float csum[4] = {0.f, 0.f, 0.f, 0.f};
#pragma unroll
    for (int m = 0; m < 8; ++m)
#pragma unroll
      for (int n = 0; n < 4; ++n)
#pragma unroll
        for (int j = 0; j < 4; ++j) {
          float x = acc[m][n][j];
          float s = 1.f / (1.f + __expf(-x));   // sigmoid
          float v = __expf(s);                  // in (1, e)
          int row = row0 + wr * 128 + m * 16 + rr + j;
          int col = col0 + wc * 64 + n * 16 + cc;
          C[(long long)row * Ndim + col] = f2h(v);
          csum[n] += v;
        }
#pragma unroll
    for (int n = 0; n < 4; ++n) {
      float v = csum[n];
      v += __shfl_xor(v, 16, 64);
      v += __shfl_xor(v, 32, 64);
      if ((lane >> 4) == 0)
        atomicAdd(&colsum[(long long)bz * csld + col0 + wc * 64 + n * 16 + cc], v);
    }
  } else {
    float* C = (float*)Cp + (long long)bz * sCb;
#pragma unroll
    for (int m = 0; m < 8; ++m)
#pragma unroll
      for (int n = 0; n < 4; ++n)
#pragma unroll
        for (int j = 0; j < 4; ++j) {
          int row = row0 + wr * 128 + m * 16 + rr + j;
          int col = col0 + wc * 64 + n * 16 + cc;
          C[(long long)row * Ndim + col] = acc[m][n][j] * (1.0f / 2048.0f);
        }
  }
}

// ---------- launch ----------
// ws layout (bytes):
//   S      @ 0          : 16*2048*2048*2 = 134217728
//   zM     @ 134217728  : 16*2048*512*2  =  33554432
//   zH/eT  @ 167772160  :                  33554432   (z fp16; reused as eT)
//   eH     @ 201326592  :                  33554432
//   Mt     @ 234881024  :                    524288
//   colsum @ 235405312  : 16*2048*4      =    131072
extern "C" void kernel_launch(void* const* d_in, const int* in_sizes, int n_in,
                              void* d_out, int out_size, void* d_ws, size_t ws_size,
                              hipStream_t stream) {
  const float* z = (const float*)d_in[0];
  const float* e = (const float*)d_in[1];
  const float* M = (const float*)d_in[2];
  float* out = (float*)d_out;
  char* ws = (char*)d_ws;

  u16* S    = (u16*)(ws + 0LL);
  u16* zM   = (u16*)(ws + 134217728LL);
  u16* zH   = (u16*)(ws + 167772160LL);
  u16* eH   = (u16*)(ws + 201326592LL);
  u16* Mt   = (u16*)(ws + 234881024LL);
  float* cs = (float*)(ws + 235405312LL);

  (void)hipFuncSetAttribute(reinterpret_cast<const void*>(&k_gemm<0, 512>),
                            hipFuncAttributeMaxDynamicSharedMemorySize, 131072);
  (void)hipFuncSetAttribute(reinterpret_cast<const void*>(&k_gemm<1, 512>),
                            hipFuncAttributeMaxDynamicSharedMemorySize, 131072);
  (void)hipFuncSetAttribute(reinterpret_cast<const void*>(&k_gemm<2, 2048>),
                            hipFuncAttributeMaxDynamicSharedMemorySize, 131072);

  hipMemsetAsync(cs, 0, (size_t)BB * NE * sizeof(float), stream);

  k_cvt<<<4096, 256, 0, stream>>>(z, zH, BB * NZ * DD / 4);
  k_cvt<<<4096, 256, 0, stream>>>(e, eH, BB * NE * DD / 4);
  k_mt<<<dim3(16, 16), dim3(32, 8), 0, stream>>>(M, Mt);

  // zM[32768 x 512] = zH @ Mt^T   (batch folded into rows); 256 blocks
  k_gemm<0, 512><<<dim3(DD / 256, (BB * NZ) / 256, 1), 512, 131072, stream>>>(
      zH, Mt, zM, DD, 0LL, 0LL, 0LL, nullptr, 0);

  // S[b] = exp(sigmoid(zM[b] @ eH[b]^T)) ; colsum atomics; 1024 blocks
  k_gemm<1, 512><<<dim3(NE / 256, NZ / 256, BB), 512, 131072, stream>>>(
      zM, eH, S, NE,
      (long long)NZ * DD, (long long)NE * DD, (long long)NZ * NE, cs, NE);

  // eT'[b][d][m] = fp16(eH[b][m][d] * 2048 / colsum[b][m])   (reuses zH region)
  u16* eT = zH;
  k_et<<<dim3(DD / 32, NE / 32, BB), dim3(32, 8), 0, stream>>>(eH, cs, eT);

  // out[b] = (S[b] @ eT[b]^T) / 2048 ; 256 blocks
  k_gemm<2, 2048><<<dim3(DD / 256, NZ / 256, BB), 512, 131072, stream>>>(
      S, eT, out, DD,
      (long long)NZ * NE, (long long)DD * NE, (long long)NZ * DD, nullptr, 0);
}